// Round 7
// baseline (138.444 us; speedup 1.0000x reference)
//
#include <hip/hip_runtime.h>
#include <hip/hip_bf16.h>
#include <math.h>

#define EPSV 1e-5f
#define AROW 40   // bf16 row stride: 80B = 5 quartets, gcd(5,8)=1 -> balanced banks
#define HSTR 129  // f32 row stride in tail kernel: (129*r+k)%32 distinct per r

typedef __attribute__((ext_vector_type(8))) short bf16x8;   // 8 bf16 = 4 VGPRs
typedef __attribute__((ext_vector_type(4))) float f32x4;

// ---------------------------------------------------------------------------
// prep: bf16 hi/lo MFMA B-operand tables for the 9 particle-varying W0 rows.
// wt[i], i = n*32 + k: whi duplicated in k=0..15 and k=16..31 halves (wt1),
// wlo duplicated (wt2). With A = [hi k0..8 | lo k16..24], two MFMAs give the
// exact (ahi+alo)*(whi+wlo) product.
__global__ __launch_bounds__(256) void prep_weights(
    const float* __restrict__ W0,
    __hip_bfloat16* __restrict__ wt1, __hip_bfloat16* __restrict__ wt2)
{
    const int RV[9] = {0, 1, 2, 3, 14, 15, 16, 17, 18};
    for (int i = threadIdx.x; i < 128 * 32; i += 256) {
        const int n  = i >> 5;
        const int kk = i & 15;
        float val = 0.0f;
        if (n < 127 && kk < 9) val = W0[RV[kk] * 127 + n];
        const __hip_bfloat16 hi = __float2bfloat16(val);
        const __hip_bfloat16 lo = __float2bfloat16(val - __bfloat162float(hi));
        wt1[i] = hi;
        wt2[i] = lo;
    }
}

// ---------------------------------------------------------------------------
// halo_pool: ONE WAVE per (b,t). 64 lanes process 256 particles (4 each).
// No cross-wave sync: v-mean and pooling via xor-shuffles; __syncthreads in a
// single-wave workgroup is just a waitcnt. B-frags prefetched to registers at
// kernel top (R6 lesson: in-loop global B loads stall the MFMA loop).
// Output: pooled layer-0 activations hvec[bt][128] -> hbuf (global ws).
__global__ __launch_bounds__(64, 2) void halo_pool(
    const float* __restrict__ x0g, const float* __restrict__ xg,
    const int*   __restrict__ Ng,  const float* __restrict__ basisg,
    const float* __restrict__ vg,  const float* __restrict__ W0,
    const float* __restrict__ b0,
    const __hip_bfloat16* __restrict__ wt1g,
    const __hip_bfloat16* __restrict__ wt2g,
    float* __restrict__ hbuf, int Tn)
{
    __shared__ __align__(16) __hip_bfloat16 SA[256 * AROW];  // A rows (hi|lo)
    __shared__ float cvec[128];

    const int bt   = blockIdx.x;
    const int b    = bt / Tn;
    const int lane = threadIdx.x;      // 0..63
    const int quad = lane >> 4;
    const int lm   = lane & 15;

    // ---- B-fragment prefetch (no dependencies -> hidden under everything) ----
    bf16x8 bh[8], bl[8];
    #pragma unroll
    for (int nt = 0; nt < 8; ++nt) {
        const int woff = (nt*16 + lm) * 32 + quad * 8;
        bh[nt] = *reinterpret_cast<const bf16x8*>(&wt1g[woff]);
        bl[nt] = *reinterpret_cast<const bf16x8*>(&wt2g[woff]);
    }

    // ---- particle loads: lane owns particles {j*64+lane} ----
    const long gbase = (long)bt * 256 * 3;
    float px[4][3], pv[4][3];
    #pragma unroll
    for (int j = 0; j < 4; ++j) {
        const int p = j*64 + lane;
        #pragma unroll
        for (int c = 0; c < 3; ++c) {
            px[j][c] = xg[gbase + p*3 + c];
            pv[j][c] = vg[gbase + p*3 + c];
        }
    }

    // ---- v0 = mean over 256 particles: local sum + xor-shuffle reduce ----
    float s0 = pv[0][0]+pv[1][0]+pv[2][0]+pv[3][0];
    float s1 = pv[0][1]+pv[1][1]+pv[2][1]+pv[3][1];
    float s2 = pv[0][2]+pv[1][2]+pv[2][2]+pv[3][2];
    #pragma unroll
    for (int m = 1; m < 64; m <<= 1) {
        s0 += __shfl_xor(s0, m);
        s1 += __shfl_xor(s1, m);
        s2 += __shfl_xor(s2, m);
    }
    const float inv_nd = 1.0f / 256.0f;
    const float v00 = s0 * inv_nd, v01 = s1 * inv_nd, v02 = s2 * inv_nd;

    // ---- per-(b,t) scalars (uniform -> scalar loads) ----
    const float p0 = x0g[bt*3+0], p1 = x0g[bt*3+1], p2 = x0g[bt*3+2];
    float bas[3][3];
    #pragma unroll
    for (int k = 0; k < 3; ++k)
        #pragma unroll
        for (int c = 0; c < 3; ++c)
            bas[k][c] = basisg[(b*3 + k)*3 + c];

    const float x0n  = sqrtf(p0*p0 + p1*p1 + p2*p2) + EPSV;
    const float ix0n = 1.0f / x0n;
    const float x0u0 = p0*ix0n, x0u1 = p1*ix0n, x0u2 = p2*ix0n;

    const float v0n  = sqrtf(v00*v00 + v01*v01 + v02*v02) + EPSV;
    const float iv0n = 1.0f / v0n;
    const float v0u0 = v00*iv0n, v0u1 = v01*iv0n, v0u2 = v02*iv0n;

    const float logN = log1pf((float)Ng[bt]);

    // ---- exact fp32 constant-feature contribution, 2 cols per lane ----
    {
        float fc[10];
        fc[0] = logN;
        fc[1] = x0n;
        fc[2] = x0u0*bas[0][0] + x0u1*bas[0][1] + x0u2*bas[0][2];
        fc[3] = x0u0*bas[1][0] + x0u1*bas[1][1] + x0u2*bas[1][2];
        fc[4] = x0u0*bas[2][0] + x0u1*bas[2][1] + x0u2*bas[2][2];
        fc[5] = v0n;
        fc[6] = v0u0*bas[0][0] + v0u1*bas[0][1] + v0u2*bas[0][2];
        fc[7] = v0u0*bas[1][0] + v0u1*bas[1][1] + v0u2*bas[1][2];
        fc[8] = v0u0*bas[2][0] + v0u1*bas[2][1] + v0u2*bas[2][2];
        fc[9] = x0u0*v0u0 + x0u1*v0u1 + x0u2*v0u2;
        #pragma unroll
        for (int h = 0; h < 2; ++h) {
            const int n = lane + h*64;
            float c = 0.0f;
            if (n < 127) {
                c = b0[n];
                #pragma unroll
                for (int i = 0; i < 10; ++i)
                    c = fmaf(fc[i], W0[(4 + i) * 127 + n], c);
            }
            cvec[n] = c;
        }
    }

    // ---- features for 4 particles -> staged A rows (4x ds_write_b128 each) ----
    #pragma unroll
    for (int j = 0; j < 4; ++j) {
        const float xi0 = px[j][0], xi1 = px[j][1], xi2 = px[j][2];
        const float xn  = sqrtf(xi0*xi0 + xi1*xi1 + xi2*xi2) + EPSV;
        const float ixn = 1.0f / xn;
        const float xu0 = xi0*ixn, xu1 = xi1*ixn, xu2 = xi2*ixn;

        const float c0 = pv[j][0] - v00, c1 = pv[j][1] - v01, c2 = pv[j][2] - v02;
        const float vn  = sqrtf(c0*c0 + c1*c1 + c2*c2) + EPSV;
        const float ivn = 1.0f / vn;
        const float vu0 = c0*ivn, vu1 = c1*ivn, vu2 = c2*ivn;

        float f[9];
        f[0] = xn;                                            // W0 row 0
        f[1] = xu0*bas[0][0] + xu1*bas[0][1] + xu2*bas[0][2]; // row 1
        f[2] = xu0*bas[1][0] + xu1*bas[1][1] + xu2*bas[1][2]; // row 2
        f[3] = xu0*bas[2][0] + xu1*bas[2][1] + xu2*bas[2][2]; // row 3
        f[4] = vn;                                            // row 14
        f[5] = vu0*bas[0][0] + vu1*bas[0][1] + vu2*bas[0][2]; // row 15
        f[6] = vu0*bas[1][0] + vu1*bas[1][1] + vu2*bas[1][2]; // row 16
        f[7] = vu0*bas[2][0] + vu1*bas[2][1] + vu2*bas[2][2]; // row 17
        f[8] = xu0*vu0 + xu1*vu1 + xu2*vu2;                   // row 18

        __hip_bfloat16 row[32];
        #pragma unroll
        for (int kk = 0; kk < 32; ++kk) row[kk] = __float2bfloat16(0.0f);
        #pragma unroll
        for (int kk = 0; kk < 9; ++kk) {
            const __hip_bfloat16 hi = __float2bfloat16(f[kk]);
            row[kk]      = hi;
            row[16 + kk] = __float2bfloat16(f[kk] - __bfloat162float(hi));
        }
        bf16x8* dst = reinterpret_cast<bf16x8*>(&SA[(j*64 + lane) * AROW]);
        const bf16x8* src = reinterpret_cast<const bf16x8*>(row);
        dst[0] = src[0]; dst[1] = src[1]; dst[2] = src[2]; dst[3] = src[3];
    }
    __syncthreads();   // single-wave workgroup: compiles to waitcnt, no barrier wait

    // ---- layer 0 MFMA + leaky + pool over all 256 particles ----
    float cl[8];
    #pragma unroll
    for (int nt = 0; nt < 8; ++nt) cl[nt] = cvec[nt*16 + lm];

    float pooled[8];
    #pragma unroll
    for (int nt = 0; nt < 8; ++nt) pooled[nt] = 0.0f;

    const f32x4 zero = {0.f, 0.f, 0.f, 0.f};
    #pragma unroll 4
    for (int mt = 0; mt < 16; ++mt) {
        const bf16x8 af = *reinterpret_cast<const bf16x8*>(
            &SA[(mt*16 + lm) * AROW + quad*8]);
        #pragma unroll
        for (int nt = 0; nt < 8; ++nt) {
            f32x4 acc = __builtin_amdgcn_mfma_f32_16x16x32_bf16(af, bh[nt], zero, 0, 0, 0);
            acc = __builtin_amdgcn_mfma_f32_16x16x32_bf16(af, bl[nt], acc, 0, 0, 0);
            #pragma unroll
            for (int r = 0; r < 4; ++r) {
                const float d = acc[r] + cl[nt];
                pooled[nt] += fmaxf(d, 0.01f*d);     // leaky_relu
            }
        }
    }
    #pragma unroll
    for (int nt = 0; nt < 8; ++nt) {
        pooled[nt] += __shfl_xor(pooled[nt], 16);
        pooled[nt] += __shfl_xor(pooled[nt], 32);
    }
    if (lane < 16) {
        #pragma unroll
        for (int nt = 0; nt < 8; ++nt) {
            const int n = nt*16 + lane;
            hbuf[(long)bt * 128 + n] = (n < 127) ? pooled[nt] * inv_nd : logN;
        }
    }
}

// ---------------------------------------------------------------------------
// tail_mlp: batched 2-layer MLP on pooled vectors. One block per 16 (b,t)
// rows -> W1/W2 traffic amortized x16 (R6 read 128KB of weights per (b,t)).
__global__ __launch_bounds__(256) void tail_mlp(
    const float* __restrict__ hbuf, const float* __restrict__ W1,
    const float* __restrict__ b1,   const float* __restrict__ W2,
    const float* __restrict__ b2,   const float* __restrict__ Pg,
    float* __restrict__ out, int Tn, int BT)
{
    __shared__ float Hl[16 * HSTR];
    __shared__ float H1[16 * HSTR];

    const int t    = threadIdx.x;
    const int row0 = blockIdx.x * 16;

    // load 16 rows x 128 (coalesced float4 -> padded LDS)
    #pragma unroll
    for (int it = 0; it < 2; ++it) {
        const int l = (t + it*256) * 4;        // 0..2044
        const long g = (long)row0 * 128 + l;
        if (row0 + (l >> 7) < BT) {
            const float4 h4 = *reinterpret_cast<const float4*>(&hbuf[g]);
            const int r = l >> 7, c = l & 127;
            Hl[r*HSTR + c+0] = h4.x;
            Hl[r*HSTR + c+1] = h4.y;
            Hl[r*HSTR + c+2] = h4.z;
            Hl[r*HSTR + c+3] = h4.w;
        }
    }
    __syncthreads();

    const int r  = t >> 4;       // 0..15: local row
    const int j0 = (t & 15) * 8; // 8 output cols

    float a[8];
    #pragma unroll
    for (int q = 0; q < 8; ++q) a[q] = b1[j0 + q];
    #pragma unroll 4
    for (int k = 0; k < 128; ++k) {
        const float hk = Hl[r*HSTR + k];
        const float4 wa = *reinterpret_cast<const float4*>(&W1[k*128 + j0]);
        const float4 wb = *reinterpret_cast<const float4*>(&W1[k*128 + j0 + 4]);
        a[0] = fmaf(hk, wa.x, a[0]);  a[1] = fmaf(hk, wa.y, a[1]);
        a[2] = fmaf(hk, wa.z, a[2]);  a[3] = fmaf(hk, wa.w, a[3]);
        a[4] = fmaf(hk, wb.x, a[4]);  a[5] = fmaf(hk, wb.y, a[5]);
        a[6] = fmaf(hk, wb.z, a[6]);  a[7] = fmaf(hk, wb.w, a[7]);
    }
    #pragma unroll
    for (int q = 0; q < 8; ++q) {
        const float x = a[q];
        H1[r*HSTR + j0 + q] = fmaxf(x, 0.01f*x);
    }
    __syncthreads();

    #pragma unroll
    for (int q = 0; q < 8; ++q) a[q] = b2[j0 + q];
    #pragma unroll 4
    for (int k = 0; k < 128; ++k) {
        const float hk = H1[r*HSTR + k];
        const float4 wa = *reinterpret_cast<const float4*>(&W2[k*128 + j0]);
        const float4 wb = *reinterpret_cast<const float4*>(&W2[k*128 + j0 + 4]);
        a[0] = fmaf(hk, wa.x, a[0]);  a[1] = fmaf(hk, wa.y, a[1]);
        a[2] = fmaf(hk, wa.z, a[2]);  a[3] = fmaf(hk, wa.w, a[3]);
        a[4] = fmaf(hk, wb.x, a[4]);  a[5] = fmaf(hk, wb.y, a[5]);
        a[6] = fmaf(hk, wb.z, a[6]);  a[7] = fmaf(hk, wb.w, a[7]);
    }

    const int grow = row0 + r;
    if (grow < BT) {
        const float sc = 1.0f / Pg[grow / Tn];
        float4 o;
        o.x = a[0]*sc; o.y = a[1]*sc; o.z = a[2]*sc; o.w = a[3]*sc;
        *reinterpret_cast<float4*>(&out[(long)grow*128 + j0]) = o;
        o.x = a[4]*sc; o.y = a[5]*sc; o.z = a[6]*sc; o.w = a[7]*sc;
        *reinterpret_cast<float4*>(&out[(long)grow*128 + j0 + 4]) = o;
    }
}

extern "C" void kernel_launch(void* const* d_in, const int* in_sizes, int n_in,
                              void* d_out, int out_size, void* d_ws, size_t ws_size,
                              hipStream_t stream) {
    const float* x0    = (const float*)d_in[0];
    const float* x     = (const float*)d_in[1];
    const int*   N     = (const int*)  d_in[2];
    const float* basis = (const float*)d_in[3];
    const float* v     = (const float*)d_in[4];
    const float* P200c = (const float*)d_in[5];
    const float* W0    = (const float*)d_in[6];
    const float* b0    = (const float*)d_in[7];
    const float* W1    = (const float*)d_in[8];
    const float* b1    = (const float*)d_in[9];
    const float* W2    = (const float*)d_in[10];
    const float* b2    = (const float*)d_in[11];
    float* out = (float*)d_out;

    const int B  = in_sizes[5];             // P200c is [B]
    const int T  = in_sizes[2] / B;         // N is [B,T]
    const int BT = B * T;

    char* ws = (char*)d_ws;
    __hip_bfloat16* wt1  = (__hip_bfloat16*)(ws);
    __hip_bfloat16* wt2  = (__hip_bfloat16*)(ws + 8192);
    float*          hbuf = (float*)(ws + 16384);

    hipLaunchKernelGGL(prep_weights, dim3(1), dim3(256), 0, stream, W0, wt1, wt2);

    hipLaunchKernelGGL(halo_pool, dim3(BT), dim3(64), 0, stream,
                       x0, x, N, basis, v, W0, b0, wt1, wt2, hbuf, T);

    hipLaunchKernelGGL(tail_mlp, dim3((BT + 15) / 16), dim3(256), 0, stream,
                       hbuf, W1, b1, W2, b2, P200c, out, T, BT);
}

// Round 8
// 113.199 us; speedup vs baseline: 1.2230x; 1.2230x over previous
//
#include <hip/hip_runtime.h>
#include <hip/hip_bf16.h>
#include <math.h>

#define EPSV 1e-5f
#define HD   128
#define AROW 40   // bf16 row stride: 80B = 5 bank-quartets, gcd(5,8)=1 -> balanced
#define WROW 40

typedef __attribute__((ext_vector_type(8))) short bf16x8;   // 8 bf16 = 4 VGPRs
typedef __attribute__((ext_vector_type(4))) float f32x4;

// One block per (b,t). blockDim = 256 = ND. 4 waves. Single dispatch (R7
// lesson: each extra dispatch costs ~6-10us fixed; R5's 1-dispatch shape was
// the best total). 5 barriers (R5 had 7). Feature rows + Wt rows written as
// ds_write_b128 at stride-80B (R5's scalar b16 writes cost 1.57M conflict cy).
// Layer 0: 10 per-(b,t)-constant features -> exact fp32 cvec[n]; 9 varying
// features -> compensated bf16 MFMA (A: hi k0..8 | lo k16..24; B1=[whi|whi],
// B2=[wlo|wlo] => 2 MFMAs give exact (ahi+alo)*(whi+wlo)).
__global__ __launch_bounds__(256, 3) void net_fused(
    const float* __restrict__ x0g, const float* __restrict__ xg,
    const int*   __restrict__ Ng,  const float* __restrict__ basisg,
    const float* __restrict__ vg,  const float* __restrict__ Pg,
    const float* __restrict__ W0,  const float* __restrict__ b0,
    const float* __restrict__ W1,  const float* __restrict__ b1,
    const float* __restrict__ W2,  const float* __restrict__ b2,
    float* __restrict__ out, int Tn, int NDn)
{
    __shared__ __align__(16) __hip_bfloat16 SA[256 * AROW];   // A rows (hi|lo)
    __shared__ __align__(16) __hip_bfloat16 Wt1[128 * WROW];  // [whi|whi]
    __shared__ __align__(16) __hip_bfloat16 Wt2[128 * WROW];  // [wlo|wlo]
    __shared__ float cvec[HD];        // exact constant-feature contribution
    __shared__ float part[4][HD];     // per-wave pooled partials
    __shared__ float hvec[HD];        // pooled + logN
    __shared__ float h1vec[HD];       // layer-1 activations
    __shared__ float vred[4][3];      // v-mean wave partials

    const int bt   = blockIdx.x;
    const int b    = bt / Tn;
    const int tid  = threadIdx.x;
    const int lane = tid & 63;
    const int wave = tid >> 6;

    // ---- per-particle global loads (particle i = tid) ----
    const long pbase = ((long)bt * NDn + tid) * 3;
    const float xi0 = xg[pbase+0], xi1 = xg[pbase+1], xi2 = xg[pbase+2];
    const float vi0 = vg[pbase+0], vi1 = vg[pbase+1], vi2 = vg[pbase+2];

    // ---- v0 mean: wave shuffle reduce -> vred ----
    float s0 = vi0, s1 = vi1, s2 = vi2;
    #pragma unroll
    for (int off = 32; off > 0; off >>= 1) {
        s0 += __shfl_down(s0, off);
        s1 += __shfl_down(s1, off);
        s2 += __shfl_down(s2, off);
    }
    if (lane == 0) { vred[wave][0] = s0; vred[wave][1] = s1; vred[wave][2] = s2; }

    // ---- Wt staging by threads 0..127 (independent of vred; same barrier) ----
    if (tid < 128) {
        const int RV[9] = {0, 1, 2, 3, 14, 15, 16, 17, 18};
        __hip_bfloat16 r1[32], r2[32];
        #pragma unroll
        for (int kk = 0; kk < 32; ++kk) {
            r1[kk] = __float2bfloat16(0.0f);
            r2[kk] = __float2bfloat16(0.0f);
        }
        if (tid < 127) {
            #pragma unroll
            for (int kk = 0; kk < 9; ++kk) {
                const float wv = W0[RV[kk] * 127 + tid];   // coalesced across tid
                const __hip_bfloat16 hi = __float2bfloat16(wv);
                const __hip_bfloat16 lo = __float2bfloat16(wv - __bfloat162float(hi));
                r1[kk] = hi;  r1[16 + kk] = hi;
                r2[kk] = lo;  r2[16 + kk] = lo;
            }
        }
        bf16x8* d1 = reinterpret_cast<bf16x8*>(&Wt1[tid * WROW]);
        bf16x8* d2 = reinterpret_cast<bf16x8*>(&Wt2[tid * WROW]);
        const bf16x8* s1v = reinterpret_cast<const bf16x8*>(r1);
        const bf16x8* s2v = reinterpret_cast<const bf16x8*>(r2);
        d1[0]=s1v[0]; d1[1]=s1v[1]; d1[2]=s1v[2]; d1[3]=s1v[3];
        d2[0]=s2v[0]; d2[1]=s2v[1]; d2[2]=s2v[2]; d2[3]=s2v[3];
    }
    __syncthreads();                                             // B1

    const float inv_nd = 1.0f / (float)NDn;
    const float v00 = (vred[0][0]+vred[1][0]+vred[2][0]+vred[3][0]) * inv_nd;
    const float v01 = (vred[0][1]+vred[1][1]+vred[2][1]+vred[3][1]) * inv_nd;
    const float v02 = (vred[0][2]+vred[1][2]+vred[2][2]+vred[3][2]) * inv_nd;

    // ---- per-(b,t) scalars ----
    const float p0 = x0g[bt*3+0], p1 = x0g[bt*3+1], p2 = x0g[bt*3+2];
    float bas[3][3];
    #pragma unroll
    for (int k = 0; k < 3; ++k)
        #pragma unroll
        for (int c = 0; c < 3; ++c)
            bas[k][c] = basisg[(b*3 + k)*3 + c];

    const float x0n  = sqrtf(p0*p0 + p1*p1 + p2*p2) + EPSV;
    const float ix0n = 1.0f / x0n;
    const float x0u0 = p0*ix0n, x0u1 = p1*ix0n, x0u2 = p2*ix0n;

    const float v0n  = sqrtf(v00*v00 + v01*v01 + v02*v02) + EPSV;
    const float iv0n = 1.0f / v0n;
    const float v0u0 = v00*iv0n, v0u1 = v01*iv0n, v0u2 = v02*iv0n;

    const float logN = log1pf((float)Ng[bt]);

    // ---- exact fp32 constant-feature contribution (W0 rows 4..13) ----
    if (tid < 128) {
        float c = 0.0f;
        if (tid < 127) {
            float fc[10];
            fc[0] = logN;
            fc[1] = x0n;
            fc[2] = x0u0*bas[0][0] + x0u1*bas[0][1] + x0u2*bas[0][2];
            fc[3] = x0u0*bas[1][0] + x0u1*bas[1][1] + x0u2*bas[1][2];
            fc[4] = x0u0*bas[2][0] + x0u1*bas[2][1] + x0u2*bas[2][2];
            fc[5] = v0n;
            fc[6] = v0u0*bas[0][0] + v0u1*bas[0][1] + v0u2*bas[0][2];
            fc[7] = v0u0*bas[1][0] + v0u1*bas[1][1] + v0u2*bas[1][2];
            fc[8] = v0u0*bas[2][0] + v0u1*bas[2][1] + v0u2*bas[2][2];
            fc[9] = x0u0*v0u0 + x0u1*v0u1 + x0u2*v0u2;
            c = b0[tid];
            #pragma unroll
            for (int i = 0; i < 10; ++i)
                c = fmaf(fc[i], W0[(4 + i) * 127 + tid], c);
        }
        cvec[tid] = c;
    }

    // ---- per-particle varying features -> SA row via 4x ds_write_b128 ----
    {
        const float xn  = sqrtf(xi0*xi0 + xi1*xi1 + xi2*xi2) + EPSV;
        const float ixn = 1.0f / xn;
        const float xu0 = xi0*ixn, xu1 = xi1*ixn, xu2 = xi2*ixn;

        const float c0 = vi0 - v00, c1 = vi1 - v01, c2 = vi2 - v02;
        const float vn  = sqrtf(c0*c0 + c1*c1 + c2*c2) + EPSV;
        const float ivn = 1.0f / vn;
        const float vu0 = c0*ivn, vu1 = c1*ivn, vu2 = c2*ivn;

        float f[9];
        f[0] = xn;                                            // W0 row 0
        f[1] = xu0*bas[0][0] + xu1*bas[0][1] + xu2*bas[0][2]; // row 1
        f[2] = xu0*bas[1][0] + xu1*bas[1][1] + xu2*bas[1][2]; // row 2
        f[3] = xu0*bas[2][0] + xu1*bas[2][1] + xu2*bas[2][2]; // row 3
        f[4] = vn;                                            // row 14
        f[5] = vu0*bas[0][0] + vu1*bas[0][1] + vu2*bas[0][2]; // row 15
        f[6] = vu0*bas[1][0] + vu1*bas[1][1] + vu2*bas[1][2]; // row 16
        f[7] = vu0*bas[2][0] + vu1*bas[2][1] + vu2*bas[2][2]; // row 17
        f[8] = xu0*vu0 + xu1*vu1 + xu2*vu2;                   // row 18

        __hip_bfloat16 row[32];
        #pragma unroll
        for (int kk = 0; kk < 32; ++kk) row[kk] = __float2bfloat16(0.0f);
        #pragma unroll
        for (int kk = 0; kk < 9; ++kk) {
            const __hip_bfloat16 hi = __float2bfloat16(f[kk]);
            row[kk]      = hi;
            row[16 + kk] = __float2bfloat16(f[kk] - __bfloat162float(hi));
        }
        bf16x8* dst = reinterpret_cast<bf16x8*>(&SA[tid * AROW]);
        const bf16x8* src = reinterpret_cast<const bf16x8*>(row);
        dst[0] = src[0]; dst[1] = src[1]; dst[2] = src[2]; dst[3] = src[3];
    }
    __syncthreads();                                             // B2

    // ---- layer 0 MFMA: wave w owns particles [w*64, w*64+64) x 128 cols ----
    {
        const int quad = lane >> 4;
        const int lm   = lane & 15;

        bf16x8 bf1[8], bf2[8];
        float  cl[8];
        #pragma unroll
        for (int nt = 0; nt < 8; ++nt) {
            bf1[nt] = *reinterpret_cast<const bf16x8*>(&Wt1[(nt*16 + lm) * WROW + quad*8]);
            bf2[nt] = *reinterpret_cast<const bf16x8*>(&Wt2[(nt*16 + lm) * WROW + quad*8]);
            cl[nt]  = cvec[nt*16 + lm];
        }

        float pooled[8];
        #pragma unroll
        for (int nt = 0; nt < 8; ++nt) pooled[nt] = 0.0f;

        const f32x4 zero = {0.f, 0.f, 0.f, 0.f};
        #pragma unroll
        for (int mt = 0; mt < 4; ++mt) {
            const bf16x8 af = *reinterpret_cast<const bf16x8*>(
                &SA[(wave*64 + mt*16 + lm) * AROW + quad*8]);
            #pragma unroll
            for (int nt = 0; nt < 8; ++nt) {
                f32x4 acc = __builtin_amdgcn_mfma_f32_16x16x32_bf16(af, bf1[nt], zero, 0, 0, 0);
                acc = __builtin_amdgcn_mfma_f32_16x16x32_bf16(af, bf2[nt], acc, 0, 0, 0);
                #pragma unroll
                for (int r = 0; r < 4; ++r) {
                    const float d = acc[r] + cl[nt];
                    pooled[nt] += fmaxf(d, 0.01f*d);     // leaky_relu
                }
            }
        }
        #pragma unroll
        for (int nt = 0; nt < 8; ++nt) {
            pooled[nt] += __shfl_xor(pooled[nt], 16);
            pooled[nt] += __shfl_xor(pooled[nt], 32);
        }
        if (lane < 16) {
            #pragma unroll
            for (int nt = 0; nt < 8; ++nt)
                part[wave][nt*16 + lane] = pooled[nt];
        }
    }
    __syncthreads();                                             // B3

    if (tid < HD) {
        const float p = part[0][tid] + part[1][tid] + part[2][tid] + part[3][tid];
        hvec[tid] = (tid < 127) ? p * inv_nd : logN;
    }
    __syncthreads();                                             // B4

    // ---- layer 1: thread j full-K GEMV; W loads coalesced across j ----
    if (tid < HD) {
        float a = b1[tid];
        #pragma unroll 16
        for (int k = 0; k < HD; ++k)
            a = fmaf(hvec[k], W1[k*HD + tid], a);
        h1vec[tid] = fmaxf(a, 0.01f*a);
    }
    __syncthreads();                                             // B5

    // ---- layer 2 + output scale ----
    if (tid < HD) {
        float a = b2[tid];
        #pragma unroll 16
        for (int k = 0; k < HD; ++k)
            a = fmaf(h1vec[k], W2[k*HD + tid], a);
        out[(long)bt * HD + tid] = a / Pg[b];
    }
}

extern "C" void kernel_launch(void* const* d_in, const int* in_sizes, int n_in,
                              void* d_out, int out_size, void* d_ws, size_t ws_size,
                              hipStream_t stream) {
    const float* x0    = (const float*)d_in[0];
    const float* x     = (const float*)d_in[1];
    const int*   N     = (const int*)  d_in[2];
    const float* basis = (const float*)d_in[3];
    const float* v     = (const float*)d_in[4];
    const float* P200c = (const float*)d_in[5];
    const float* W0    = (const float*)d_in[6];
    const float* b0    = (const float*)d_in[7];
    const float* W1    = (const float*)d_in[8];
    const float* b1    = (const float*)d_in[9];
    const float* W2    = (const float*)d_in[10];
    const float* b2    = (const float*)d_in[11];
    float* out = (float*)d_out;

    const int B  = in_sizes[5];                 // P200c is [B]
    const int T  = in_sizes[2] / B;             // N is [B,T]
    const int ND = in_sizes[1] / (in_sizes[2] * 3);  // x is [B,T,ND,3]

    hipLaunchKernelGGL(net_fused, dim3(B * T), dim3(256), 0, stream,
                       x0, x, N, basis, v, P200c, W0, b0, W1, b1, W2, b2,
                       out, T, ND);
}

// Round 9
// 111.320 us; speedup vs baseline: 1.2437x; 1.0169x over previous
//
#include <hip/hip_runtime.h>
#include <hip/hip_bf16.h>
#include <math.h>

#define EPSV 1e-5f
#define HD   128
#define AROW 40   // SA bf16 row stride: 80B = 5 quartets, gcd(5,8)=1 -> balanced
#define WROW 24   // Wt bf16 row stride: 48B = 3 quartets, gcd(3,8)=1 -> balanced

typedef __attribute__((ext_vector_type(8))) short bf16x8;   // 8 bf16 = 4 VGPRs
typedef __attribute__((ext_vector_type(4))) float f32x4;

// One block per (b,t). blockDim = 256 = ND. 4 waves. Single dispatch.
// R9 changes vs R8 (38us): Wt halved (quads 2/3 re-read rows 0/1's data ->
// 16-wide rows, offset (quad&1)*8), pooling via ds_add_f32 into hvec (kills
// the part[] combine + one barrier), cvec folded into MFMA acc init
// (acc={cl,cl,cl,cl}; all 4 C/D rows of a tile share the column). LDS
// 44.6->33.5KB -> 4 blocks/CU (was 3).
// Numerics: 10 per-(b,t)-constant features exact fp32 (cvec); 9 varying
// features compensated bf16 MFMA (A: hi k0..8 | lo k16..24; B1=whi, B2=wlo
// read twice => exact (ahi+alo)*(whi+wlo)).
__global__ __launch_bounds__(256, 4) void net_fused(
    const float* __restrict__ x0g, const float* __restrict__ xg,
    const int*   __restrict__ Ng,  const float* __restrict__ basisg,
    const float* __restrict__ vg,  const float* __restrict__ Pg,
    const float* __restrict__ W0,  const float* __restrict__ b0,
    const float* __restrict__ W1,  const float* __restrict__ b1,
    const float* __restrict__ W2,  const float* __restrict__ b2,
    float* __restrict__ out, int Tn, int NDn)
{
    __shared__ __align__(16) __hip_bfloat16 SA[256 * AROW];   // A rows (hi|lo)
    __shared__ __align__(16) __hip_bfloat16 Wt1[128 * WROW];  // whi (16 used/row)
    __shared__ __align__(16) __hip_bfloat16 Wt2[128 * WROW];  // wlo
    __shared__ float cvec[HD];        // exact constant-feature contribution
    __shared__ float hvec[HD];        // pooled (atomic-accumulated) + logN
    __shared__ float h1vec[HD];       // layer-1 activations
    __shared__ float vred[4][3];      // v-mean wave partials

    const int bt   = blockIdx.x;
    const int b    = bt / Tn;
    const int tid  = threadIdx.x;
    const int lane = tid & 63;
    const int wave = tid >> 6;

    // ---- per-particle global loads (particle i = tid) ----
    const long pbase = ((long)bt * NDn + tid) * 3;
    const float xi0 = xg[pbase+0], xi1 = xg[pbase+1], xi2 = xg[pbase+2];
    const float vi0 = vg[pbase+0], vi1 = vg[pbase+1], vi2 = vg[pbase+2];

    // ---- v0 mean: wave shuffle reduce -> vred ----
    float s0 = vi0, s1 = vi1, s2 = vi2;
    #pragma unroll
    for (int off = 32; off > 0; off >>= 1) {
        s0 += __shfl_down(s0, off);
        s1 += __shfl_down(s1, off);
        s2 += __shfl_down(s2, off);
    }
    if (lane == 0) { vred[wave][0] = s0; vred[wave][1] = s1; vred[wave][2] = s2; }

    // ---- Wt staging by threads 0..127 (independent of vred; same barrier) ----
    if (tid < 128) {
        const int RV[9] = {0, 1, 2, 3, 14, 15, 16, 17, 18};
        __hip_bfloat16 r1[16], r2[16];
        #pragma unroll
        for (int kk = 0; kk < 16; ++kk) {
            r1[kk] = __float2bfloat16(0.0f);
            r2[kk] = __float2bfloat16(0.0f);
        }
        if (tid < 127) {
            #pragma unroll
            for (int kk = 0; kk < 9; ++kk) {
                const float wv = W0[RV[kk] * 127 + tid];   // coalesced across tid
                const __hip_bfloat16 hi = __float2bfloat16(wv);
                r1[kk] = hi;
                r2[kk] = __float2bfloat16(wv - __bfloat162float(hi));
            }
        }
        bf16x8* d1 = reinterpret_cast<bf16x8*>(&Wt1[tid * WROW]);
        bf16x8* d2 = reinterpret_cast<bf16x8*>(&Wt2[tid * WROW]);
        const bf16x8* s1v = reinterpret_cast<const bf16x8*>(r1);
        const bf16x8* s2v = reinterpret_cast<const bf16x8*>(r2);
        d1[0] = s1v[0]; d1[1] = s1v[1];
        d2[0] = s2v[0]; d2[1] = s2v[1];
    }
    __syncthreads();                                             // B1

    const float inv_nd = 1.0f / (float)NDn;
    const float v00 = (vred[0][0]+vred[1][0]+vred[2][0]+vred[3][0]) * inv_nd;
    const float v01 = (vred[0][1]+vred[1][1]+vred[2][1]+vred[3][1]) * inv_nd;
    const float v02 = (vred[0][2]+vred[1][2]+vred[2][2]+vred[3][2]) * inv_nd;

    // ---- per-(b,t) scalars ----
    const float p0 = x0g[bt*3+0], p1 = x0g[bt*3+1], p2 = x0g[bt*3+2];
    float bas[3][3];
    #pragma unroll
    for (int k = 0; k < 3; ++k)
        #pragma unroll
        for (int c = 0; c < 3; ++c)
            bas[k][c] = basisg[(b*3 + k)*3 + c];

    const float x0n  = sqrtf(p0*p0 + p1*p1 + p2*p2) + EPSV;
    const float ix0n = 1.0f / x0n;
    const float x0u0 = p0*ix0n, x0u1 = p1*ix0n, x0u2 = p2*ix0n;

    const float v0n  = sqrtf(v00*v00 + v01*v01 + v02*v02) + EPSV;
    const float iv0n = 1.0f / v0n;
    const float v0u0 = v00*iv0n, v0u1 = v01*iv0n, v0u2 = v02*iv0n;

    const float logN = log1pf((float)Ng[bt]);

    // ---- exact fp32 constant-feature contribution + hvec init ----
    if (tid < 128) {
        float c = 0.0f;
        if (tid < 127) {
            float fc[10];
            fc[0] = logN;
            fc[1] = x0n;
            fc[2] = x0u0*bas[0][0] + x0u1*bas[0][1] + x0u2*bas[0][2];
            fc[3] = x0u0*bas[1][0] + x0u1*bas[1][1] + x0u2*bas[1][2];
            fc[4] = x0u0*bas[2][0] + x0u1*bas[2][1] + x0u2*bas[2][2];
            fc[5] = v0n;
            fc[6] = v0u0*bas[0][0] + v0u1*bas[0][1] + v0u2*bas[0][2];
            fc[7] = v0u0*bas[1][0] + v0u1*bas[1][1] + v0u2*bas[1][2];
            fc[8] = v0u0*bas[2][0] + v0u1*bas[2][1] + v0u2*bas[2][2];
            fc[9] = x0u0*v0u0 + x0u1*v0u1 + x0u2*v0u2;
            c = b0[tid];
            #pragma unroll
            for (int i = 0; i < 10; ++i)
                c = fmaf(fc[i], W0[(4 + i) * 127 + tid], c);
        }
        cvec[tid] = c;
        hvec[tid] = (tid == 127) ? logN : 0.0f;   // atomic-accumulation base
    }

    // ---- per-particle varying features -> SA row via 4x ds_write_b128 ----
    {
        const float xn  = sqrtf(xi0*xi0 + xi1*xi1 + xi2*xi2) + EPSV;
        const float ixn = 1.0f / xn;
        const float xu0 = xi0*ixn, xu1 = xi1*ixn, xu2 = xi2*ixn;

        const float c0 = vi0 - v00, c1 = vi1 - v01, c2 = vi2 - v02;
        const float vn  = sqrtf(c0*c0 + c1*c1 + c2*c2) + EPSV;
        const float ivn = 1.0f / vn;
        const float vu0 = c0*ivn, vu1 = c1*ivn, vu2 = c2*ivn;

        float f[9];
        f[0] = xn;                                            // W0 row 0
        f[1] = xu0*bas[0][0] + xu1*bas[0][1] + xu2*bas[0][2]; // row 1
        f[2] = xu0*bas[1][0] + xu1*bas[1][1] + xu2*bas[1][2]; // row 2
        f[3] = xu0*bas[2][0] + xu1*bas[2][1] + xu2*bas[2][2]; // row 3
        f[4] = vn;                                            // row 14
        f[5] = vu0*bas[0][0] + vu1*bas[0][1] + vu2*bas[0][2]; // row 15
        f[6] = vu0*bas[1][0] + vu1*bas[1][1] + vu2*bas[1][2]; // row 16
        f[7] = vu0*bas[2][0] + vu1*bas[2][1] + vu2*bas[2][2]; // row 17
        f[8] = xu0*vu0 + xu1*vu1 + xu2*vu2;                   // row 18

        __hip_bfloat16 row[32];
        #pragma unroll
        for (int kk = 0; kk < 32; ++kk) row[kk] = __float2bfloat16(0.0f);
        #pragma unroll
        for (int kk = 0; kk < 9; ++kk) {
            const __hip_bfloat16 hi = __float2bfloat16(f[kk]);
            row[kk]      = hi;
            row[16 + kk] = __float2bfloat16(f[kk] - __bfloat162float(hi));
        }
        bf16x8* dst = reinterpret_cast<bf16x8*>(&SA[tid * AROW]);
        const bf16x8* src = reinterpret_cast<const bf16x8*>(row);
        dst[0] = src[0]; dst[1] = src[1]; dst[2] = src[2]; dst[3] = src[3];
    }
    __syncthreads();                                             // B2

    // ---- layer 0 MFMA: wave w owns particles [w*64, w*64+64) x 128 cols ----
    {
        const int quad = lane >> 4;
        const int lm   = lane & 15;
        const int koff = (quad & 1) * 8;    // quads 2/3 re-read rows' same data

        bf16x8 bf1[8], bf2[8];
        f32x4  cin[8];
        #pragma unroll
        for (int nt = 0; nt < 8; ++nt) {
            bf1[nt] = *reinterpret_cast<const bf16x8*>(&Wt1[(nt*16 + lm) * WROW + koff]);
            bf2[nt] = *reinterpret_cast<const bf16x8*>(&Wt2[(nt*16 + lm) * WROW + koff]);
            const float cl = cvec[nt*16 + lm];
            cin[nt] = (f32x4){cl, cl, cl, cl};   // all 4 C/D rows share column n
        }

        float pooled[8];
        #pragma unroll
        for (int nt = 0; nt < 8; ++nt) pooled[nt] = 0.0f;

        #pragma unroll
        for (int mt = 0; mt < 4; ++mt) {
            const bf16x8 af = *reinterpret_cast<const bf16x8*>(
                &SA[(wave*64 + mt*16 + lm) * AROW + quad*8]);
            #pragma unroll
            for (int nt = 0; nt < 8; ++nt) {
                f32x4 acc = __builtin_amdgcn_mfma_f32_16x16x32_bf16(af, bf1[nt], cin[nt], 0, 0, 0);
                acc = __builtin_amdgcn_mfma_f32_16x16x32_bf16(af, bf2[nt], acc, 0, 0, 0);
                #pragma unroll
                for (int r = 0; r < 4; ++r)
                    pooled[nt] += fmaxf(acc[r], 0.01f*acc[r]);   // leaky_relu
            }
        }
        #pragma unroll
        for (int nt = 0; nt < 8; ++nt) {
            pooled[nt] += __shfl_xor(pooled[nt], 16);
            pooled[nt] += __shfl_xor(pooled[nt], 32);
        }
        if (lane < 16) {
            #pragma unroll
            for (int nt = 0; nt < 8; ++nt) {
                const int n = nt*16 + lane;
                if (n < 127) atomicAdd(&hvec[n], pooled[nt] * inv_nd);  // ds_add_f32
            }
        }
    }
    __syncthreads();                                             // B3

    // ---- layer 1: thread j full-K GEMV; W loads coalesced across j ----
    if (tid < HD) {
        float a = b1[tid];
        #pragma unroll 16
        for (int k = 0; k < HD; ++k)
            a = fmaf(hvec[k], W1[k*HD + tid], a);
        h1vec[tid] = fmaxf(a, 0.01f*a);
    }
    __syncthreads();                                             // B4

    // ---- layer 2 + output scale ----
    if (tid < HD) {
        float a = b2[tid];
        #pragma unroll 16
        for (int k = 0; k < HD; ++k)
            a = fmaf(h1vec[k], W2[k*HD + tid], a);
        out[(long)bt * HD + tid] = a / Pg[b];
    }
}

extern "C" void kernel_launch(void* const* d_in, const int* in_sizes, int n_in,
                              void* d_out, int out_size, void* d_ws, size_t ws_size,
                              hipStream_t stream) {
    const float* x0    = (const float*)d_in[0];
    const float* x     = (const float*)d_in[1];
    const int*   N     = (const int*)  d_in[2];
    const float* basis = (const float*)d_in[3];
    const float* v     = (const float*)d_in[4];
    const float* P200c = (const float*)d_in[5];
    const float* W0    = (const float*)d_in[6];
    const float* b0    = (const float*)d_in[7];
    const float* W1    = (const float*)d_in[8];
    const float* b1    = (const float*)d_in[9];
    const float* W2    = (const float*)d_in[10];
    const float* b2    = (const float*)d_in[11];
    float* out = (float*)d_out;

    const int B  = in_sizes[5];                 // P200c is [B]
    const int T  = in_sizes[2] / B;             // N is [B,T]
    const int ND = in_sizes[1] / (in_sizes[2] * 3);  // x is [B,T,ND,3]

    hipLaunchKernelGGL(net_fused, dim3(B * T), dim3(256), 0, stream,
                       x0, x, N, basis, v, P200c, W0, b0, W1, b1, W2, b2,
                       out, T, ND);
}